// Round 1
// baseline (5791.682 us; speedup 1.0000x reference)
//
#include <hip/hip_runtime.h>
#include <hip/hip_bf16.h>

#define NIMG 2
#define NOBJ 64
#define NREL 256
#define CH   512
#define HH   38
#define WW   38
#define HWSZ 1444
#define PL   7

// ---------------------------------------------------------------------------
// Generic f32 tiled GEMM: C[M,N] = A[M,K] @ B[K,N] (+bias) (+relu)
// TRANSA: A stored (K,M) row-major. BIASMODE: 0 none, 1 per-col, 2 per-row.
// Batched via blockIdx.z with element strides sA/sB/sC. K must be %16==0.
// ---------------------------------------------------------------------------
template<bool TRANSA, int BIASMODE, bool RELU>
__global__ __launch_bounds__(256)
void gemm_f32(int M, int N, int K,
              const float* __restrict__ A, int lda, long long sA,
              const float* __restrict__ B, int ldb, long long sB,
              float* __restrict__ C, int ldc, long long sC,
              const float* __restrict__ bias)
{
    __shared__ float As[16][64];
    __shared__ float Bs[16][64];
    const int bz = blockIdx.z;
    A += (size_t)bz * sA; B += (size_t)bz * sB; C += (size_t)bz * sC;
    const int bm = blockIdx.y * 64, bn = blockIdx.x * 64;
    const int tx = threadIdx.x, ty = threadIdx.y;
    const int tid = ty * 16 + tx;
    float acc[4][4] = {};
    for (int bk = 0; bk < K; bk += 16) {
        if (TRANSA) {
            int k = tid >> 4, m4 = (tid & 15) << 2;
            const float* Ar = A + (size_t)(bk + k) * lda + (bm + m4);
            #pragma unroll
            for (int i = 0; i < 4; ++i)
                As[k][m4 + i] = (bm + m4 + i < M) ? Ar[i] : 0.f;
        } else {
            int m = tid >> 2, k4 = (tid & 3) << 2;
            const float* Ar = A + (size_t)(bm + m) * lda + (bk + k4);
            #pragma unroll
            for (int i = 0; i < 4; ++i)
                As[k4 + i][m] = (bm + m < M) ? Ar[i] : 0.f;
        }
        {
            int k = tid >> 4, n4 = (tid & 15) << 2;
            const float* Br = B + (size_t)(bk + k) * ldb + (bn + n4);
            #pragma unroll
            for (int i = 0; i < 4; ++i)
                Bs[k][n4 + i] = (bn + n4 + i < N) ? Br[i] : 0.f;
        }
        __syncthreads();
        #pragma unroll
        for (int kk = 0; kk < 16; ++kk) {
            float a[4], b[4];
            #pragma unroll
            for (int i = 0; i < 4; ++i) a[i] = As[kk][ty * 4 + i];
            #pragma unroll
            for (int j = 0; j < 4; ++j) b[j] = Bs[kk][tx * 4 + j];
            #pragma unroll
            for (int i = 0; i < 4; ++i)
                #pragma unroll
                for (int j = 0; j < 4; ++j)
                    acc[i][j] += a[i] * b[j];
        }
        __syncthreads();
    }
    #pragma unroll
    for (int i = 0; i < 4; ++i) {
        int row = bm + ty * 4 + i;
        if (row >= M) continue;
        #pragma unroll
        for (int j = 0; j < 4; ++j) {
            int col = bn + tx * 4 + j;
            if (col >= N) continue;
            float v = acc[i][j];
            if (BIASMODE == 1) v += bias[col];
            if (BIASMODE == 2) v += bias[row];
            if (RELU) v = fmaxf(v, 0.f);
            C[(size_t)row * ldc + col] = v;
        }
    }
}

// ---------------------------------------------------------------------------
// Per-object box setup: bilinear indices/weights + dedup'd hw->slot map
// ---------------------------------------------------------------------------
__global__ void setup_boxes(const float* __restrict__ boxes,
                            int* __restrict__ sampSlot,   // (NOBJ, HWSZ)
                            int* __restrict__ metaI,      // (NOBJ, 28) y0,y1,x0,x1
                            float* __restrict__ metaF)    // (NOBJ, 14) wy,wx
{
    const int n = blockIdx.x, tid = threadIdx.x;
    for (int hw = tid; hw < HWSZ; hw += 256) sampSlot[n * HWSZ + hw] = -1;
    __syncthreads();
    if (tid == 0) {
        float b0 = boxes[n*4+0] / 16.f, b1 = boxes[n*4+1] / 16.f;
        float b2 = boxes[n*4+2] / 16.f, b3 = boxes[n*4+3] / 16.f;
        int y0i[7], y1i[7], x0i[7], x1i[7];
        for (int i = 0; i < 7; ++i) {
            float g  = (i + 0.5f) / 7.f;
            float ys = b1 + (b3 - b1) * g;
            float xs = b0 + (b2 - b0) * g;
            float y0 = floorf(ys), x0 = floorf(xs);
            float wy = ys - y0,    wx = xs - x0;
            int y0c = min(max((int)y0, 0), HH - 1); int y1c = min(y0c + 1, HH - 1);
            int x0c = min(max((int)x0, 0), WW - 1); int x1c = min(x0c + 1, WW - 1);
            y0i[i] = y0c; y1i[i] = y1c; x0i[i] = x0c; x1i[i] = x1c;
            metaI[n*28 + i]      = y0c; metaI[n*28 + 7  + i] = y1c;
            metaI[n*28 + 14 + i] = x0c; metaI[n*28 + 21 + i] = x1c;
            metaF[n*14 + i] = wy;  metaF[n*14 + 7 + i] = wx;
        }
        int ns = 0;
        for (int sy = 0; sy < 14; ++sy) {
            int y = (sy < 7) ? y0i[sy] : y1i[sy - 7];
            for (int sx = 0; sx < 14; ++sx) {
                int x = (sx < 7) ? x0i[sx] : x1i[sx - 7];
                int hw = y * WW + x;
                if (sampSlot[n * HWSZ + hw] < 0) sampSlot[n * HWSZ + hw] = ns++;
            }
        }
    }
}

// ---------------------------------------------------------------------------
// Depthwise 3x3 SAME conv per object (generated filters) -> bf16 + BN stats
// ---------------------------------------------------------------------------
__global__ __launch_bounds__(256)
void dwconv_bn_stats(const float* __restrict__ rf,       // (NIMG, CH, HWSZ)
                     const float* __restrict__ dwf,      // (NOBJ, CH*9)
                     const int* __restrict__ im_inds,
                     __hip_bfloat16* __restrict__ dw16,  // (NOBJ, CH, HWSZ)
                     float* __restrict__ dwSum, float* __restrict__ dwSq)
{
    const int n = blockIdx.x >> 9, c = blockIdx.x & 511;
    const int tid = threadIdx.x;
    const int im = im_inds[n];
    const float* src = rf + ((size_t)im * CH + c) * HWSZ;
    const float* kp  = dwf + (size_t)n * (CH * 9) + c * 9;
    float k9[9];
    #pragma unroll
    for (int t = 0; t < 9; ++t) k9[t] = kp[t];
    __hip_bfloat16* dst = dw16 + ((size_t)n * CH + c) * HWSZ;
    float lsum = 0.f, lsq = 0.f;
    for (int hw = tid; hw < HWSZ; hw += 256) {
        int y = hw / WW, x = hw - y * WW;
        float s = 0.f;
        #pragma unroll
        for (int dy = 0; dy < 3; ++dy) {
            int yy = y + dy - 1;
            if (yy < 0 || yy >= HH) continue;
            #pragma unroll
            for (int dx = 0; dx < 3; ++dx) {
                int xx = x + dx - 1;
                if (xx < 0 || xx >= WW) continue;
                s += src[yy * WW + xx] * k9[dy * 3 + dx];
            }
        }
        __hip_bfloat16 h = __float2bfloat16(s);
        dst[hw] = h;
        float v = __bfloat162float(h);
        lsum += v; lsq += v * v;
    }
    __shared__ float sred[2][256];
    sred[0][tid] = lsum; sred[1][tid] = lsq;
    __syncthreads();
    for (int off = 128; off > 0; off >>= 1) {
        if (tid < off) { sred[0][tid] += sred[0][tid+off]; sred[1][tid] += sred[1][tid+off]; }
        __syncthreads();
    }
    if (tid == 0) { atomicAdd(&dwSum[c], sred[0][0]); atomicAdd(&dwSq[c], sred[1][0]); }
}

// ---------------------------------------------------------------------------
// BN finalize: inv = scale/sqrt(var+eps), beta = bias - mean*inv
// ---------------------------------------------------------------------------
__global__ void bn_finalize(const float* __restrict__ sum, const float* __restrict__ sq,
                            const float* __restrict__ scale, const float* __restrict__ bias,
                            float* __restrict__ inv, float* __restrict__ beta, float cnt)
{
    int c = blockIdx.x * 256 + threadIdx.x;
    if (c < CH) {
        float m  = sum[c] / cnt;
        float v  = sq[c] / cnt - m * m;
        float iv = scale[c] / sqrtf(v + 1e-5f);
        inv[c] = iv; beta[c] = bias[c] - m * iv;
    }
}

// ---------------------------------------------------------------------------
// pw einsum: pw[n,d,hw] = sum_c pwf[n,d,c] * (dw16[n,c,hw]*dwInv[c]+dwBeta[c])
// Accumulates exact BN stats (atomics) and writes ONLY sampled columns.
// grid (23, 8, 64), block (16,16)
// ---------------------------------------------------------------------------
__global__ __launch_bounds__(256)
void einsum_pw(const float* __restrict__ pwf,            // (NOBJ, CH, CH)
               const __hip_bfloat16* __restrict__ dw16,  // (NOBJ, CH, HWSZ)
               const float* __restrict__ dwInv, const float* __restrict__ dwBeta,
               const int* __restrict__ sampSlot,         // (NOBJ, HWSZ)
               float* __restrict__ pwSamp,               // (NOBJ, CH, 196)
               float* __restrict__ pwSum, float* __restrict__ pwSq)
{
    const int n  = blockIdx.z;
    const int bm = blockIdx.y * 64, bn = blockIdx.x * 64;
    const int tx = threadIdx.x, ty = threadIdx.y;
    const int tid = ty * 16 + tx;
    __shared__ float As[16][64];
    __shared__ float Bs[16][64];
    const float* A = pwf + (size_t)n * CH * CH;
    const __hip_bfloat16* Bb = dw16 + (size_t)n * CH * HWSZ;
    float acc[4][4] = {};
    for (int bk = 0; bk < CH; bk += 16) {
        {
            int m = tid >> 2, k4 = (tid & 3) << 2;
            const float* Ar = A + (size_t)(bm + m) * CH + bk + k4;
            #pragma unroll
            for (int i = 0; i < 4; ++i) As[k4 + i][m] = Ar[i];
        }
        {
            int k = tid >> 4, n4 = (tid & 15) << 2;
            int kg = bk + k;
            float iv = dwInv[kg], bt = dwBeta[kg];
            const __hip_bfloat16* Br = Bb + (size_t)kg * HWSZ + bn + n4;
            #pragma unroll
            for (int i = 0; i < 4; ++i) {
                int col = bn + n4 + i;
                Bs[k][n4 + i] = (col < HWSZ) ? (__bfloat162float(Br[i]) * iv + bt) : 0.f;
            }
        }
        __syncthreads();
        #pragma unroll
        for (int kk = 0; kk < 16; ++kk) {
            float a[4], b[4];
            #pragma unroll
            for (int i = 0; i < 4; ++i) a[i] = As[kk][ty * 4 + i];
            #pragma unroll
            for (int j = 0; j < 4; ++j) b[j] = Bs[kk][tx * 4 + j];
            #pragma unroll
            for (int i = 0; i < 4; ++i)
                #pragma unroll
                for (int j = 0; j < 4; ++j)
                    acc[i][j] += a[i] * b[j];
        }
        __syncthreads();
    }
    // per-block BN stats reduction (rows = d channels)
    __shared__ float rs[64], rq[64];
    if (tid < 64) { rs[tid] = 0.f; rq[tid] = 0.f; }
    __syncthreads();
    #pragma unroll
    for (int i = 0; i < 4; ++i) {
        float s = 0.f, q = 0.f;
        #pragma unroll
        for (int j = 0; j < 4; ++j) {
            int col = bn + tx * 4 + j;
            if (col < HWSZ) { float v = acc[i][j]; s += v; q += v * v; }
        }
        atomicAdd(&rs[ty * 4 + i], s);
        atomicAdd(&rq[ty * 4 + i], q);
    }
    __syncthreads();
    if (tid < 64) {
        atomicAdd(&pwSum[bm + tid], rs[tid]);
        atomicAdd(&pwSq [bm + tid], rq[tid]);
    }
    // write sampled columns (raw pre-BN values)
    #pragma unroll
    for (int j = 0; j < 4; ++j) {
        int col = bn + tx * 4 + j;
        if (col < HWSZ) {
            int s = sampSlot[n * HWSZ + col];
            if (s >= 0) {
                #pragma unroll
                for (int i = 0; i < 4; ++i)
                    pwSamp[((size_t)(n * CH + bm + ty * 4 + i)) * 196 + s] = acc[i][j];
            }
        }
    }
}

// ---------------------------------------------------------------------------
// ROI 7x7 bilinear pool per object with fused pw-BN + relu -> P (NOBJ,CH,49)
// ---------------------------------------------------------------------------
__global__ __launch_bounds__(256)
void roi_pool(const float* __restrict__ pwSamp, const int* __restrict__ sampSlot,
              const int* __restrict__ metaI, const float* __restrict__ metaF,
              const float* __restrict__ pwInv, const float* __restrict__ pwBeta,
              float* __restrict__ P)
{
    const int n = blockIdx.x, tid = threadIdx.x;
    __shared__ int   sSlot[196];
    __shared__ float sW[196];
    if (tid < 196) {
        int ij = tid >> 2, corner = tid & 3;
        int i = ij / 7, j = ij - 7 * i;
        int y = (corner & 2) ? metaI[n*28 + 7 + i]  : metaI[n*28 + i];
        int x = (corner & 1) ? metaI[n*28 + 21 + j] : metaI[n*28 + 14 + j];
        float wy = metaF[n*14 + i], wx = metaF[n*14 + 7 + j];
        float w = ((corner & 2) ? wy : 1.f - wy) * ((corner & 1) ? wx : 1.f - wx);
        sSlot[tid] = sampSlot[n * HWSZ + y * WW + x];
        sW[tid] = w;
    }
    __syncthreads();
    for (int idx = tid; idx < CH * 49; idx += 256) {
        int c = idx / 49, ij = idx - 49 * c;
        float iv = pwInv[c], bt = pwBeta[c];
        const float* base = pwSamp + ((size_t)(n * CH + c)) * 196;
        float v = 0.f;
        #pragma unroll
        for (int corner = 0; corner < 4; ++corner) {
            int s = sSlot[ij * 4 + corner];
            float val = fmaxf(base[s] * iv + bt, 0.f);
            v += sW[ij * 4 + corner] * val;
        }
        P[((size_t)(n * CH + c)) * 49 + ij] = v;
    }
}

// ---------------------------------------------------------------------------
// small elementwise kernels
// ---------------------------------------------------------------------------
__global__ void qx_row128(const float* __restrict__ recover_b, float* __restrict__ Qx)
{
    int i = blockIdx.x * 256 + threadIdx.x;
    if (i < 25088) Qx[(size_t)128 * 25088 + i] = recover_b[i / 49];
}

__global__ void h1_kernel(const float* __restrict__ U, const float* __restrict__ fc1_b,
                          const int* __restrict__ rel_inds, float* __restrict__ h1)
{
    int r = blockIdx.y;
    int j = blockIdx.x * 256 + threadIdx.x;
    int s = rel_inds[r * 2], o = rel_inds[r * 2 + 1];
    float v = U[(size_t)s * 4096 + j] + U[(size_t)(64 + o) * 4096 + j]
            + U[(size_t)128 * 4096 + j] + fc1_b[j];
    h1[(size_t)r * 4096 + j] = fmaxf(v, 0.f);
}

__global__ void cat_kernel(const float* __restrict__ subobj, const int* __restrict__ rel_inds,
                           float* __restrict__ cat)
{
    int r = blockIdx.y;
    int k = blockIdx.x * 256 + threadIdx.x;
    int s = rel_inds[r * 2], o = rel_inds[r * 2 + 1];
    cat[(size_t)r * 1024 + k] = (k < 512) ? subobj[(size_t)s * 1024 + k]
                                          : subobj[(size_t)o * 1024 + k];
}

__global__ void triple_kernel(const float* __restrict__ lo, const float* __restrict__ lr,
                              float* __restrict__ trip)
{
    int r = blockIdx.y;
    int k = blockIdx.x * 256 + threadIdx.x;
    float a = lo[(size_t)r * 1536 + k], b = lr[(size_t)r * 1536 + k];
    trip[(size_t)r * 1536 + k] = fmaxf(a + b, 0.f) - (a - b) * (a - b);
}

// ---------------------------------------------------------------------------
extern "C" void kernel_launch(void* const* d_in, const int* in_sizes, int n_in,
                              void* d_out, int out_size, void* d_ws, size_t ws_size,
                              hipStream_t stream)
{
    const float* fmaps      = (const float*)d_in[0];
    const float* boxes      = (const float*)d_in[1];
    const float* rof        = (const float*)d_in[2];
    const float* reduce_w   = (const float*)d_in[3];
    const float* reduce_b   = (const float*)d_in[4];
    const float* dw_gen_w   = (const float*)d_in[5];
    const float* dw_gen_b   = (const float*)d_in[6];
    const float* pw_gen_w   = (const float*)d_in[7];
    const float* pw_gen_b   = (const float*)d_in[8];
    const float* dw_bn_s    = (const float*)d_in[9];
    const float* dw_bn_b    = (const float*)d_in[10];
    const float* pw_bn_s    = (const float*)d_in[11];
    const float* pw_bn_b    = (const float*)d_in[12];
    const float* recover_w  = (const float*)d_in[13];
    const float* recover_b  = (const float*)d_in[14];
    const float* fc1_w      = (const float*)d_in[15];
    const float* fc1_b      = (const float*)d_in[16];
    const float* fc2_w      = (const float*)d_in[17];
    const float* fc2_b      = (const float*)d_in[18];
    const float* post_obj_w = (const float*)d_in[19];
    const float* post_obj_b = (const float*)d_in[20];
    const float* mapping_w  = (const float*)d_in[21];
    const float* mapping_b  = (const float*)d_in[22];
    const float* rel_red_w  = (const float*)d_in[23];
    const float* rel_red_b  = (const float*)d_in[24];
    const float* comp_w     = (const float*)d_in[25];
    const float* comp_b     = (const float*)d_in[26];
    const int*   im_inds    = (const int*)d_in[27];
    const int*   rel_inds   = (const int*)d_in[28];
    float* out = (float*)d_out;

    // ---- workspace carve (~231 MB) ----
    char* p = (char*)d_ws;
    auto alloc = [&](size_t bytes) { char* r = p; p += (bytes + 255) & ~(size_t)255; return r; };
    float*          rf       = (float*)alloc((size_t)NIMG * CH * HWSZ * 4);
    float*          dwf      = (float*)alloc((size_t)NOBJ * CH * 9 * 4);
    float*          pwf      = (float*)alloc((size_t)NOBJ * CH * CH * 4);
    __hip_bfloat16* dw16     = (__hip_bfloat16*)alloc((size_t)NOBJ * CH * HWSZ * 2);
    int*            sampSlot = (int*)alloc((size_t)NOBJ * HWSZ * 4);
    int*            metaI    = (int*)alloc((size_t)NOBJ * 28 * 4);
    float*          metaF    = (float*)alloc((size_t)NOBJ * 14 * 4);
    float*          stats    = (float*)alloc((size_t)8 * CH * 4);
    float* dwSum = stats,          *dwSq  = stats + CH;
    float* pwSum = stats + 2*CH,   *pwSq  = stats + 3*CH;
    float* dwInv = stats + 4*CH,   *dwBeta= stats + 5*CH;
    float* pwInv = stats + 6*CH,   *pwBeta= stats + 7*CH;
    float*          pwSamp   = (float*)alloc((size_t)NOBJ * CH * 196 * 4);
    float*          P        = (float*)alloc((size_t)NOBJ * CH * 49 * 4);
    float*          Qx       = (float*)alloc((size_t)129 * 25088 * 4);
    float*          U        = (float*)alloc((size_t)129 * 4096 * 4);
    float*          h1       = (float*)alloc((size_t)NREL * 4096 * 4);
    float*          relin    = (float*)alloc((size_t)NREL * 4096 * 4);
    float*          subobj   = (float*)alloc((size_t)NOBJ * 1024 * 4);
    float*          cat      = (float*)alloc((size_t)NREL * 1024 * 4);
    float*          lo       = (float*)alloc((size_t)NREL * 1536 * 4);
    float*          lr       = (float*)alloc((size_t)NREL * 1536 * 4);
    float*          trip     = (float*)alloc((size_t)NREL * 1536 * 4);

    dim3 blk(16, 16);

    // zero the BN-stat accumulators (dwSum,dwSq,pwSum,pwSq)
    hipMemsetAsync(stats, 0, (size_t)4 * CH * 4, stream);

    // box metadata + sample-slot map
    setup_boxes<<<NOBJ, 256, 0, stream>>>(boxes, sampSlot, metaI, metaF);

    // rf[b,o,hw] = relu(fmaps[b]^T(c,hw) x reduce_w(c,o) + reduce_b[o])
    gemm_f32<true, 2, true><<<dim3(23, 8, NIMG), blk, 0, stream>>>(
        CH, HWSZ, CH, reduce_w, CH, 0, fmaps, HWSZ, (long long)CH * HWSZ,
        rf, HWSZ, (long long)CH * HWSZ, reduce_b);

    // dwf = rof @ dw_gen_w + dw_gen_b   (64 x 4608)
    gemm_f32<false, 1, false><<<dim3(72, 1, 1), blk, 0, stream>>>(
        NOBJ, CH * 9, CH, rof, CH, 0, dw_gen_w, CH * 9, 0,
        dwf, CH * 9, 0, dw_gen_b);

    // pwf = rof @ pw_gen_w + pw_gen_b   (64 x 262144)
    gemm_f32<false, 1, false><<<dim3(4096, 1, 1), blk, 0, stream>>>(
        NOBJ, CH * CH, CH, rof, CH, 0, pw_gen_w, CH * CH, 0,
        pwf, CH * CH, 0, pw_gen_b);

    // subobj = rof @ post_obj_w + post_obj_b   (64 x 1024)
    gemm_f32<false, 1, false><<<dim3(16, 1, 1), blk, 0, stream>>>(
        NOBJ, 1024, CH, rof, CH, 0, post_obj_w, 1024, 0,
        subobj, 1024, 0, post_obj_b);

    // depthwise conv -> dw16 + dw BN stats
    dwconv_bn_stats<<<NOBJ * CH, 256, 0, stream>>>(rf, dwf, im_inds, dw16, dwSum, dwSq);
    bn_finalize<<<2, 256, 0, stream>>>(dwSum, dwSq, dw_bn_s, dw_bn_b, dwInv, dwBeta,
                                       (float)(NOBJ * HWSZ));

    // pw einsum with fused BN-on-B, stats, sampled writes
    einsum_pw<<<dim3(23, 8, NOBJ), blk, 0, stream>>>(
        pwf, dw16, dwInv, dwBeta, sampSlot, pwSamp, pwSum, pwSq);
    bn_finalize<<<2, 256, 0, stream>>>(pwSum, pwSq, pw_bn_s, pw_bn_b, pwInv, pwBeta,
                                       (float)(NOBJ * HWSZ));

    // ROI pool (fused pw BN + relu) -> P (64, 512, 49)
    roi_pool<<<NOBJ, 256, 0, stream>>>(pwSamp, sampSlot, metaI, metaF, pwInv, pwBeta, P);

    // Qx rows 0..63:  Q1[n][o][hw] = recover_w[:512]^T x P[n]
    gemm_f32<true, 0, false><<<dim3(1, 8, NOBJ), blk, 0, stream>>>(
        CH, 49, CH, recover_w, CH, 0, P, 49, (long long)CH * 49,
        Qx, 49, 25088, nullptr);
    // Qx rows 64..127: Q2 with recover_w[512:]
    gemm_f32<true, 0, false><<<dim3(1, 8, NOBJ), blk, 0, stream>>>(
        CH, 49, CH, recover_w + (size_t)CH * CH, CH, 0, P, 49, (long long)CH * 49,
        Qx + (size_t)64 * 25088, 49, 25088, nullptr);
    // Qx row 128 = recover_b broadcast over hw
    qx_row128<<<98, 256, 0, stream>>>(recover_b, Qx);

    // U = Qx @ fc1_w   (129 x 4096, K = 25088)
    gemm_f32<false, 0, false><<<dim3(64, 3, 1), blk, 0, stream>>>(
        129, 4096, 25088, Qx, 25088, 0, fc1_w, 4096, 0, U, 4096, 0, nullptr);

    // h1[r] = relu(U[s] + U[64+o] + U[128] + fc1_b)
    h1_kernel<<<dim3(16, NREL), 256, 0, stream>>>(U, fc1_b, rel_inds, h1);

    // rel_input = h1 @ fc2_w + fc2_b   (256 x 4096)
    gemm_f32<false, 1, false><<<dim3(64, 4, 1), blk, 0, stream>>>(
        NREL, 4096, 4096, h1, 4096, 0, fc2_w, 4096, 0, relin, 4096, 0, fc2_b);

    // cat[r] = [subobj[s,:512], subobj[o,512:]]
    cat_kernel<<<dim3(4, NREL), 256, 0, stream>>>(subobj, rel_inds, cat);

    // last_obj = cat @ mapping_w + mapping_b   (256 x 1536)
    gemm_f32<false, 1, false><<<dim3(24, 4, 1), blk, 0, stream>>>(
        NREL, 1536, 1024, cat, 1024, 0, mapping_w, 1536, 0, lo, 1536, 0, mapping_b);

    // last_rel = rel_input @ rel_red_w + rel_red_b   (256 x 1536)
    gemm_f32<false, 1, false><<<dim3(24, 4, 1), blk, 0, stream>>>(
        NREL, 1536, 4096, relin, 4096, 0, rel_red_w, 1536, 0, lr, 1536, 0, rel_red_b);

    // triple = relu(lo+lr) - (lo-lr)^2
    triple_kernel<<<dim3(6, NREL), 256, 0, stream>>>(lo, lr, trip);

    // out = triple @ comp_w + comp_b   (256 x 51)
    gemm_f32<false, 1, false><<<dim3(1, 4, 1), blk, 0, stream>>>(
        NREL, 51, 1536, trip, 1536, 0, comp_w, 51, 0, out, 51, 0, comp_b);
}